// Round 10
// baseline (595.600 us; speedup 1.0000x reference)
//
#include <hip/hip_runtime.h>
#include <stdint.h>

#define NPTS   131072
#define DEMB   512
#define NCL    512
#define BM     128
#define BN     128
#define NCHUNK 8
#define MT     (NPTS / BM)        // 1024
#define NT     (NCL / BN)         // 4
#define NBLK   (MT * NT)          // 4096

typedef __attribute__((ext_vector_type(4))) float f32x4;
typedef __attribute__((ext_vector_type(8))) short short8;
typedef __attribute__((ext_vector_type(8))) unsigned short us8;

// ---- workspace layout (bytes) ----
// [0, 512KB)        : bf16 centroid LDS-images: [n_tile 0..3][chunk 0..7] 16KB each,
//                     row-major [128 clusters][64 d] bf16 with slot-XOR swizzle.
// [512KB, +2KB)     : c2[k] = ||c_k||^2 (f32)
// [526336, +6MB)    : per-row tile stats [row][n_tile][3] f32 = {min, sum_e, sum_g*e}
// [6817792, +512KB) : x2[row] (f32)
// [7342080, +2KB)   : merge partial sums (512 f32)
#define WS_CB   0u
#define WS_C2   524288u
#define WS_ROW  526336u
#define WS_X2   6817792u
#define WS_PART 7342080u

static __device__ __forceinline__ unsigned short f2bf(float f) {
  union { float f; uint32_t u; } c{f};
  uint32_t r = c.u + 0x7FFFu + ((c.u >> 16) & 1u);   // round-to-nearest-even
  return (unsigned short)(r >> 16);
}
static __device__ __forceinline__ float sq4(float4 v) {
  return v.x * v.x + v.y * v.y + v.z * v.z + v.w * v.w;
}

typedef const __attribute__((address_space(1))) void gvoid;
typedef __attribute__((address_space(3))) void svoid;
static __device__ __forceinline__ void llds16(const void* g, void* s) {
  __builtin_amdgcn_global_load_lds((gvoid*)g, (svoid*)s, 16, 0, 0);
}

// ---------- prep: c2 + bf16 centroid images (per n-tile, per chunk) ----------
__global__ __launch_bounds__(128) void prep_kernel(const float* __restrict__ cent,
                                                   uint8_t* __restrict__ ws) {
  const int k = blockIdx.x;            // cluster 0..511
  const int t = threadIdx.x;           // 0..127
  float4 v = ((const float4*)(cent + (size_t)k * DEMB))[t];
  float sq = sq4(v);
#pragma unroll
  for (int m = 1; m < 64; m <<= 1) sq += __shfl_xor(sq, m, 64);
  __shared__ float red[2];
  if ((t & 63) == 0) red[t >> 6] = sq;
  __syncthreads();
  if (t == 0) ((float*)(ws + WS_C2))[k] = red[0] + red[1];

  ushort4 b;
  b.x = f2bf(v.x); b.y = f2bf(v.y); b.z = f2bf(v.z); b.w = f2bf(v.w);
  const int d = t * 4;
  const int ch = d >> 6;               // 0..7
  const int dd = d & 63;
  const int slot = dd >> 3;            // 0..7 (8B granule -> 16B slot half)
  const int within = (dd & 7) * 2;     // byte offset inside 16B slot
  const int n_tile = k >> 7;           // 0..3
  const int kl = k & 127;              // local cluster
  const uint32_t off = (uint32_t)(n_tile * 8 + ch) * 16384u + (uint32_t)kl * 128u +
                       (uint32_t)(((slot ^ (kl & 7)) << 4) + within);
  *(ushort4*)(ws + WS_CB + off) = b;
}

// ---------- main: 128x128 tile GEMM (m97 structure) + per-tile softmin stats ----------
// 256 threads = 4 waves (2x2); wave (wr,wc) owns rows [wr*64,+64) x cols [wc*64,+64).
// LDS (dynamic 64KB): A0@0, A1@16K, B0@32K, B1@48K; epilogue aliases A0.
__global__ __launch_bounds__(256, 2) void main_kernel(
    const float* __restrict__ emb, uint8_t* __restrict__ ws,
    const float* __restrict__ alphap) {
  extern __shared__ uint8_t smem[];

  const int t = threadIdx.x;
  const int w = t >> 6;                // wave 0..3
  const int l = t & 63;
  const int l15 = l & 15;
  const int lhi = l >> 4;
  const int wr = w >> 1;               // row half
  const int wc = w & 1;                // col half
  const int l7 = l15 & 7;

  // XCD-grouped bijective mapping: 4 n-tiles of an m-panel adjacent on one XCD
  const int bid = blockIdx.x;
  const int xcd = bid & 7;
  const int idx = bid >> 3;            // 0..511
  const int n_t = idx & 3;
  const int mp = xcd * 128 + (idx >> 2);   // m-panel 0..1023
  const size_t row0 = (size_t)mp * BM;
  const int col0 = n_t * BN;

  f32x4 acc[4][4];
#pragma unroll
  for (int m = 0; m < 4; ++m)
#pragma unroll
    for (int n = 0; n < 4; ++n) acc[m][n] = (f32x4){0.f, 0.f, 0.f, 0.f};

  // A staging: thread -> row r = t>>1, half h = t&1 (32 floats per chunk)
  const int r = t >> 1;
  const int h = t & 1;
  const float4* xg4 = (const float4*)emb + ((row0 + r) * DEMB + h * 32) / 4;
  float x2a = 0.f;

  const uint32_t nt8 = (uint32_t)(n_t * 8);
  const uint32_t wl_off = (uint32_t)w * 1024u + (uint32_t)l * 16u;

#define STAGE_A(AV, DST)                                                       \
  do {                                                                         \
    uint8_t* _ad = (DST);                                                      \
    _Pragma("unroll")                                                          \
    for (int j2 = 0; j2 < 4; ++j2) {                                           \
      float4 a = AV[2 * j2], b = AV[2 * j2 + 1];                               \
      x2a += sq4(a) + sq4(b);                                                  \
      us8 u;                                                                   \
      u[0] = f2bf(a.x); u[1] = f2bf(a.y); u[2] = f2bf(a.z); u[3] = f2bf(a.w);  \
      u[4] = f2bf(b.x); u[5] = f2bf(b.y); u[6] = f2bf(b.z); u[7] = f2bf(b.w);  \
      const int slot = h * 4 + j2;                                             \
      *(us8*)(_ad + r * 128 + ((slot ^ (r & 7)) << 4)) = u;                    \
    }                                                                          \
  } while (0)

  // ---- prologue: stage A[0], B[0] into buffer 0 ----
  {
    float4 av[8];
#pragma unroll
    for (int j = 0; j < 8; ++j) av[j] = xg4[j];
    STAGE_A(av, smem);
    const uint8_t* bsrc = ws + WS_CB + nt8 * 16384u + wl_off;
    uint8_t* bdst = smem + 32768 + w * 1024;
#pragma unroll
    for (int i = 0; i < 4; ++i) llds16(bsrc + i * 4096, bdst + i * 4096);
  }
  __syncthreads();

#pragma unroll
  for (int ch = 0; ch < NCHUNK; ++ch) {
    float4 av[8];
    if (ch + 1 < NCHUNK) {
      // issue next B-tile llds + next A-tile register loads
      const uint8_t* bsrc = ws + WS_CB + (nt8 + (uint32_t)(ch + 1)) * 16384u + wl_off;
      uint8_t* bdst = smem + 32768 + (((ch + 1) & 1) ? 16384 : 0) + w * 1024;
#pragma unroll
      for (int i = 0; i < 4; ++i) llds16(bsrc + i * 4096, bdst + i * 4096);
#pragma unroll
      for (int j = 0; j < 8; ++j) av[j] = xg4[(ch + 1) * 16 + j];
    }
    // compute current chunk
    const uint8_t* Acur = smem + ((ch & 1) ? 16384 : 0);
    const uint8_t* Bcur = smem + 32768 + ((ch & 1) ? 16384 : 0);
#pragma unroll
    for (int kk = 0; kk < 2; ++kk) {
      const uint32_t swz = (uint32_t)(((kk * 4 + lhi) ^ l7) << 4);
      short8 af[4], bf[4];
#pragma unroll
      for (int m = 0; m < 4; ++m)
        af[m] = *(const short8*)(Acur + (wr * 64 + m * 16 + l15) * 128 + swz);
#pragma unroll
      for (int n = 0; n < 4; ++n)
        bf[n] = *(const short8*)(Bcur + (wc * 64 + n * 16 + l15) * 128 + swz);
#pragma unroll
      for (int m = 0; m < 4; ++m)
#pragma unroll
        for (int n = 0; n < 4; ++n)
          acc[m][n] = __builtin_amdgcn_mfma_f32_16x16x32_bf16(af[m], bf[n], acc[m][n], 0, 0, 0);
    }
    if (ch + 1 < NCHUNK)
      STAGE_A(av, smem + (((ch + 1) & 1) ? 16384 : 0));
    __syncthreads();
  }
#undef STAGE_A

  // ---- epilogue: per-row partial softmin stats over this block's 128 clusters ----
  const float alpha = alphap[0];
  const float* c2g = (const float*)(ws + WS_C2);
  float c2r[4];
#pragma unroll
  for (int n = 0; n < 4; ++n) c2r[n] = c2g[col0 + wc * 64 + n * 16 + l15];

  // x2 for this block's rows (only n_t==0 writes)
  x2a += __shfl_xor(x2a, 1, 64);
  if (n_t == 0 && h == 0) ((float*)(ws + WS_X2))[row0 + r] = x2a;

  float* redmin = (float*)smem;            // [2][128]
  float* redse  = (float*)(smem + 1024);   // [2][128]
  float* redsge = (float*)(smem + 2048);   // [2][128]
  float* gmin   = (float*)(smem + 3072);   // [128]

  float rmin[4][4];
#pragma unroll
  for (int m = 0; m < 4; ++m)
#pragma unroll
    for (int i = 0; i < 4; ++i) {
      float mn = c2r[0] - 2.f * acc[m][0][i];
#pragma unroll
      for (int n = 1; n < 4; ++n) mn = fminf(mn, c2r[n] - 2.f * acc[m][n][i]);
      rmin[m][i] = mn;
    }
#pragma unroll
  for (int msk = 1; msk < 16; msk <<= 1)
#pragma unroll
    for (int m = 0; m < 4; ++m)
#pragma unroll
      for (int i = 0; i < 4; ++i)
        rmin[m][i] = fminf(rmin[m][i], __shfl_xor(rmin[m][i], msk, 64));
  if (l15 == 0) {
#pragma unroll
    for (int m = 0; m < 4; ++m)
#pragma unroll
      for (int i = 0; i < 4; ++i)
        redmin[wc * 128 + wr * 64 + m * 16 + lhi * 4 + i] = rmin[m][i];
  }
  __syncthreads();
  if (t < 128) gmin[t] = fminf(redmin[t], redmin[128 + t]);
  __syncthreads();
#pragma unroll
  for (int m = 0; m < 4; ++m) {
#pragma unroll
    for (int i = 0; i < 4; ++i) {
      const int rl = wr * 64 + m * 16 + lhi * 4 + i;
      const float M = gmin[rl];
      float se = 0.f, sge = 0.f;
#pragma unroll
      for (int n = 0; n < 4; ++n) {
        const float g = c2r[n] - 2.f * acc[m][n][i];
        const float gm = g - M;
        const float e = __expf(-alpha * gm);
        se += e;
        sge += gm * e;
      }
#pragma unroll
      for (int msk = 1; msk < 16; msk <<= 1) {
        se += __shfl_xor(se, msk, 64);
        sge += __shfl_xor(sge, msk, 64);
      }
      if (l15 == 0) {
        redse[wc * 128 + rl] = se;
        redsge[wc * 128 + rl] = sge;
      }
    }
  }
  __syncthreads();
  if (t < 128) {
    const float M = gmin[t];
    const float Se = redse[t] + redse[128 + t];
    const float Sge = redsge[t] + redsge[128 + t];
    float* dst = (float*)(ws + WS_ROW) + ((size_t)(row0 + t) * NT + n_t) * 3;
    dst[0] = M;
    dst[1] = Se;
    dst[2] = Sge + M * Se;    // absolute sum_g_e
  }
}

// ---------- merge: exact logsumexp-combine of the 4 n-tiles per row ----------
__global__ __launch_bounds__(256) void merge_kernel(const uint8_t* __restrict__ ws,
                                                    const float* __restrict__ alphap,
                                                    float* __restrict__ partials) {
  const int gid = blockIdx.x * 256 + threadIdx.x;    // row 0..131071
  const float alpha = alphap[0];
  const float* st = (const float*)(ws + WS_ROW) + (size_t)gid * NT * 3;
  float mn = st[0];
#pragma unroll
  for (int n = 1; n < NT; ++n) mn = fminf(mn, st[n * 3]);
  float At = 0.f, Bt = 0.f;
#pragma unroll
  for (int n = 0; n < NT; ++n) {
    const float wgt = __expf(-alpha * (st[n * 3] - mn));
    At += st[n * 3 + 1] * wgt;
    Bt += st[n * 3 + 2] * wgt;
  }
  float val = Bt / At + ((const float*)(ws + WS_X2))[gid];
#pragma unroll
  for (int msk = 1; msk < 64; msk <<= 1) val += __shfl_xor(val, msk, 64);
  __shared__ float red[4];
  if ((threadIdx.x & 63) == 0) red[threadIdx.x >> 6] = val;
  __syncthreads();
  if (threadIdx.x == 0)
    partials[blockIdx.x] = red[0] + red[1] + red[2] + red[3];
}

// ---------- final deterministic reduction ----------
__global__ __launch_bounds__(256) void final_kernel(const uint8_t* __restrict__ ws,
                                                    const float* __restrict__ lambdp,
                                                    float* __restrict__ out) {
  const float* partials = (const float*)(ws + WS_PART);
  const int t = threadIdx.x;
  float s = 0.f;
  for (int i = t; i < 512; i += 256) s += partials[i];
#pragma unroll
  for (int msk = 1; msk < 64; msk <<= 1) s += __shfl_xor(s, msk, 64);
  __shared__ float red[4];
  if ((t & 63) == 0) red[t >> 6] = s;
  __syncthreads();
  if (t == 0)
    out[0] = lambdp[0] * (red[0] + red[1] + red[2] + red[3]) * (1.0f / (float)NPTS);
}

extern "C" void kernel_launch(void* const* d_in, const int* in_sizes, int n_in,
                              void* d_out, int out_size, void* d_ws, size_t ws_size,
                              hipStream_t stream) {
  const float* emb = (const float*)d_in[0];
  const float* cent = (const float*)d_in[1];
  const float* alphap = (const float*)d_in[2];
  const float* lambdp = (const float*)d_in[3];
  float* out = (float*)d_out;
  uint8_t* ws = (uint8_t*)d_ws;

  (void)hipFuncSetAttribute((const void*)main_kernel,
                            hipFuncAttributeMaxDynamicSharedMemorySize, 65536);

  prep_kernel<<<NCL, 128, 0, stream>>>(cent, ws);
  main_kernel<<<NBLK, 256, 65536, stream>>>(emb, ws, alphap);
  merge_kernel<<<NPTS / 256, 256, 0, stream>>>(ws, alphap, (float*)(ws + WS_PART));
  final_kernel<<<1, 256, 0, stream>>>(ws, lambdp, out);
}

// Round 11
// 103.952 us; speedup vs baseline: 5.7296x; 5.7296x over previous
//
#include <hip/hip_runtime.h>
#include <stdint.h>

#define NPTS   131072
#define DEMB   512
#define NCL    512
#define BM     64
#define NCHUNK 8
#define NTHREADS 256
#define NBLK   (NPTS / BM)          // 2048

typedef __attribute__((ext_vector_type(4))) float f32x4;
typedef __attribute__((ext_vector_type(8))) short short8;
typedef __attribute__((ext_vector_type(8))) unsigned short us8;

// ---- workspace layout (bytes) ----
// [0, 512KB)  : bf16 centroid fragments, per (chunk, wave, kk, n, lane):
//               frag (ch,w,kk,n) is a contiguous 1KB wave-read at
//               (((ch*4+w)*2+kk)*8+n)*1024; wave w covers cols [128w,128w+128).
// [512KB,+2KB): c2[k] = ||c_k||^2 (f32)
// [514KB,+8KB): per-block partial sums (f32, 2048)
#define WS_CB   0u
#define WS_C2   (512u * 1024u)
#define WS_PART (WS_C2 + 2048u)

static __device__ __forceinline__ unsigned short f2bf(float f) {
  union { float f; uint32_t u; } c{f};
  uint32_t r = c.u + 0x7FFFu + ((c.u >> 16) & 1u);   // round-to-nearest-even
  return (unsigned short)(r >> 16);
}
static __device__ __forceinline__ float sq4(f32x4 v) {
  return v[0] * v[0] + v[1] * v[1] + v[2] * v[2] + v[3] * v[3];
}

// ---- pinned-schedule load/wait primitives (volatile asm keeps program order) ----
#define LOAD_B8(DST, BASE)                                                     \
  do {                                                                         \
    const uint8_t* _b0 = (const uint8_t*)(BASE);                               \
    const uint8_t* _b1 = _b0 + 4096;                                           \
    asm volatile("global_load_dwordx4 %0, %8, off\n\t"                         \
                 "global_load_dwordx4 %1, %8, off offset:1024\n\t"             \
                 "global_load_dwordx4 %2, %8, off offset:2048\n\t"             \
                 "global_load_dwordx4 %3, %8, off offset:3072\n\t"             \
                 "global_load_dwordx4 %4, %9, off\n\t"                         \
                 "global_load_dwordx4 %5, %9, off offset:1024\n\t"             \
                 "global_load_dwordx4 %6, %9, off offset:2048\n\t"             \
                 "global_load_dwordx4 %7, %9, off offset:3072"                 \
                 : "=&v"(DST[0]), "=&v"(DST[1]), "=&v"(DST[2]), "=&v"(DST[3]), \
                   "=&v"(DST[4]), "=&v"(DST[5]), "=&v"(DST[6]), "=&v"(DST[7])  \
                 : "v"(_b0), "v"(_b1)                                          \
                 : "memory");                                                  \
  } while (0)

#define LOAD_E4(D, P)                                                          \
  asm volatile("global_load_dwordx4 %0, %4, off\n\t"                           \
               "global_load_dwordx4 %1, %4, off offset:16\n\t"                 \
               "global_load_dwordx4 %2, %4, off offset:32\n\t"                 \
               "global_load_dwordx4 %3, %4, off offset:48"                     \
               : "=&v"(D[0]), "=&v"(D[1]), "=&v"(D[2]), "=&v"(D[3])            \
               : "v"(P)                                                        \
               : "memory")

#define WAITV(N)                                                               \
  do {                                                                         \
    asm volatile("s_waitcnt vmcnt(" #N ")" ::: "memory");                      \
    __builtin_amdgcn_sched_barrier(0);                                         \
  } while (0)

#define BAR()                                                                  \
  do {                                                                         \
    asm volatile("s_waitcnt lgkmcnt(0)" ::: "memory");                         \
    __builtin_amdgcn_s_barrier();                                              \
  } while (0)

// ---------- prep: c2 + bf16 centroid fragments in register-load layout ----------
// cluster k -> wave w=k>>7, n=(k>>4)&7, l15=k&15; d -> ch=d>>6, dd=d&63,
// kk=dd>>5, lhi=(dd>>3)&3, elem=dd&7; lane=lhi*16+l15.
__global__ __launch_bounds__(128) void prep_kernel(const float* __restrict__ cent,
                                                   uint8_t* __restrict__ ws) {
  const int k = blockIdx.x;
  const int t = threadIdx.x;
  float4 v = ((const float4*)(cent + (size_t)k * DEMB))[t];
  float sq = v.x * v.x + v.y * v.y + v.z * v.z + v.w * v.w;
#pragma unroll
  for (int m = 1; m < 64; m <<= 1) sq += __shfl_xor(sq, m, 64);
  __shared__ float red[2];
  if ((t & 63) == 0) red[t >> 6] = sq;
  __syncthreads();
  if (t == 0) ((float*)(ws + WS_C2))[k] = red[0] + red[1];

  ushort4 b;
  b.x = f2bf(v.x); b.y = f2bf(v.y); b.z = f2bf(v.z); b.w = f2bf(v.w);
  const int d = t * 4;
  const int ch = d >> 6;
  const int dd = d & 63;
  const int kk = dd >> 5;
  const int lhi = (dd >> 3) & 3;
  const int elem = dd & 7;
  const int w = k >> 7;
  const int n = (k >> 4) & 7;
  const int l15 = k & 15;
  const int lane = lhi * 16 + l15;
  const uint32_t off =
      (uint32_t)((((ch * 4 + w) * 2 + kk) * 8 + n) * 64 + lane) * 16u +
      (uint32_t)elem * 2u;
  *(ushort4*)(ws + WS_CB + off) = b;
}

// ---------- fused GEMM + softmin: 4-wave block, BM=64, full 512 cols ----------
// 2 blocks/CU co-resident (<=256 regs/thread, ~20KB LDS) -> async overlap.
__global__ __launch_bounds__(NTHREADS, 2) void main_kernel(
    const float* __restrict__ emb, const uint8_t* __restrict__ ws,
    const float* __restrict__ alphap) {
  __shared__ uint8_t Ab[2][8192];      // A dbuf [64 rows][64 d] bf16, XOR-swizzled
  __shared__ float redmin[256];        // [4 waves][64 rows]
  __shared__ float redse[256];
  __shared__ float redsge[256];
  __shared__ float gmin[64];
  __shared__ float x2s[64];

  const int t = threadIdx.x;
  const int w = t >> 6;                // wave 0..3 -> cols [128w, 128w+128)
  const int l = t & 63;
  const int l15 = l & 15;
  const int lhi = l >> 4;
  const int bid = blockIdx.x;
  const size_t row0 = (size_t)bid * BM;

  float* partials = (float*)(ws + WS_PART);

  f32x4 acc[4][8];
#pragma unroll
  for (int m = 0; m < 4; ++m)
#pragma unroll
    for (int n = 0; n < 8; ++n) acc[m][n] = (f32x4){0.f, 0.f, 0.f, 0.f};

  // x staging: thread -> row r = t>>2, float cols [q*16, q*16+16)
  const int r = t >> 2;
  const int q = t & 3;
  const float* xge = emb + (row0 + r) * DEMB + q * 16;
  uint32_t xoff[2];
#pragma unroll
  for (int j = 0; j < 2; ++j)
    xoff[j] = (uint32_t)r * 128u + (uint32_t)(((2 * q + j) ^ (r & 7)) << 4);

  float x2a = 0.f;

  // per-(ch,kk) B base: ws + ((ch*4+w)*2+kk)*8192 + l*16
  const uint8_t* fbw = ws + WS_CB + (uint32_t)w * 16384u + (uint32_t)l * 16u;

  short8 bf[16];
  f32x4 ev0[4], ev1[4];

#define STAGE_FROM(EV, DSTBUF)                                                 \
  do {                                                                         \
    uint8_t* _an = (DSTBUF);                                                   \
    _Pragma("unroll")                                                          \
    for (int j = 0; j < 2; ++j) {                                              \
      f32x4 a = EV[2 * j], b = EV[2 * j + 1];                                  \
      x2a += sq4(a) + sq4(b);                                                  \
      us8 u;                                                                   \
      u[0] = f2bf(a[0]); u[1] = f2bf(a[1]); u[2] = f2bf(a[2]); u[3] = f2bf(a[3]); \
      u[4] = f2bf(b[0]); u[5] = f2bf(b[1]); u[6] = f2bf(b[2]); u[7] = f2bf(b[3]); \
      *(us8*)(_an + xoff[j]) = u;                                              \
    }                                                                          \
  } while (0)

  // ---- prologue: E[0]->ev0, E[1]->ev1, B[0]->bf; retire E[0]; stage A[0] ----
  LOAD_E4(ev0, xge);
  LOAD_E4(ev1, xge + 64);
  LOAD_B8((&bf[0]), fbw);              // ch=0, kk=0
  LOAD_B8((&bf[8]), fbw + 8192);       // ch=0, kk=1
  WAITV(20);                           // retires E[0]; E[1]+B[0] in flight
  STAGE_FROM(ev0, &Ab[0][0]);
  BAR();

// Body ch: [top] issue E[ch+2] (4); WAITV(4) retires E[ch+1]+B[ch]
// (queue: E[ch+1], B[ch], E[ch+2]); MFMA on bf=B[ch]; stage A[ch+1] from
// E[ch+1] regs; [bottom] re-issue bf <- B[ch+1] (after last bf read: no WAW);
// BAR. Tail: body 6 WAITV(0) (B[6] newest), body 7 WAITV(0).
#define CHUNK_BODY(CH, EVN, EVS, VN)                                           \
  {                                                                            \
    if ((CH) + 2 < NCHUNK)                                                     \
      LOAD_E4(EVN, xge + ((CH) + 2) * 64);                                     \
    const uint8_t* xb = &Ab[(CH) & 1][0];                                      \
    WAITV(VN);                                                                 \
    __builtin_amdgcn_s_setprio(1);                                             \
    _Pragma("unroll")                                                          \
    for (int kk = 0; kk < 2; ++kk) {                                           \
      const uint32_t swz = (uint32_t)(((kk * 4 + lhi) ^ (l15 & 7)) << 4);      \
      short8 af[4];                                                            \
      _Pragma("unroll")                                                        \
      for (int m = 0; m < 4; ++m)                                              \
        af[m] = *(const short8*)(xb + (uint32_t)(m * 16 + l15) * 128u + swz);  \
      _Pragma("unroll")                                                        \
      for (int m = 0; m < 4; ++m)                                              \
        _Pragma("unroll")                                                      \
        for (int n = 0; n < 8; ++n)                                            \
          acc[m][n] = __builtin_amdgcn_mfma_f32_16x16x32_bf16(                 \
              af[m], bf[kk * 8 + n], acc[m][n], 0, 0, 0);                      \
    }                                                                          \
    __builtin_amdgcn_s_setprio(0);                                             \
    if ((CH) + 1 < NCHUNK) {                                                   \
      STAGE_FROM(EVS, &Ab[((CH) + 1) & 1][0]);                                 \
      const uint8_t* nb = fbw + (uint32_t)((CH) + 1) * 65536u;                 \
      LOAD_B8((&bf[0]), nb);                                                   \
      LOAD_B8((&bf[8]), nb + 8192);                                            \
    }                                                                          \
    BAR();                                                                     \
  }

  CHUNK_BODY(0, ev0, ev1, 4)
  CHUNK_BODY(1, ev1, ev0, 4)
  CHUNK_BODY(2, ev0, ev1, 4)
  CHUNK_BODY(3, ev1, ev0, 4)
  CHUNK_BODY(4, ev0, ev1, 4)
  CHUNK_BODY(5, ev1, ev0, 4)
  CHUNK_BODY(6, ev0, ev1, 0)
  CHUNK_BODY(7, ev1, ev0, 0)
#undef CHUNK_BODY
#undef STAGE_FROM

  // ---- epilogue: g = c2 - 2*s ; val_row = min + sum((g-M)e)/sum(e) + x2 ----
  const float alpha = alphap[0];
  float c2r[8];
  {
    const float* c2p = (const float*)(ws + WS_C2) + w * 128 + l15;
    asm volatile("global_load_dword %0, %8, off\n\t"
                 "global_load_dword %1, %8, off offset:64\n\t"
                 "global_load_dword %2, %8, off offset:128\n\t"
                 "global_load_dword %3, %8, off offset:192\n\t"
                 "global_load_dword %4, %8, off offset:256\n\t"
                 "global_load_dword %5, %8, off offset:320\n\t"
                 "global_load_dword %6, %8, off offset:384\n\t"
                 "global_load_dword %7, %8, off offset:448"
                 : "=&v"(c2r[0]), "=&v"(c2r[1]), "=&v"(c2r[2]), "=&v"(c2r[3]),
                   "=&v"(c2r[4]), "=&v"(c2r[5]), "=&v"(c2r[6]), "=&v"(c2r[7])
                 : "v"(c2p)
                 : "memory");
    asm volatile("s_waitcnt vmcnt(0)" ::: "memory");
    __builtin_amdgcn_sched_barrier(0);
  }

  // per-row x2: 4 threads per row (lanes 4k..4k+3, same wave)
  x2a += __shfl_xor(x2a, 1, 64);
  x2a += __shfl_xor(x2a, 2, 64);
  if ((l & 3) == 0) x2s[r] = x2a;      // one writer per row (4 waves write same val? no:
                                       // r=t>>2 spans 0..63 uniquely across block)

  float rmin[4][4];
#pragma unroll
  for (int m = 0; m < 4; ++m)
#pragma unroll
    for (int i = 0; i < 4; ++i) {
      float mn = c2r[0] - 2.f * acc[m][0][i];
#pragma unroll
      for (int n = 1; n < 8; ++n) mn = fminf(mn, c2r[n] - 2.f * acc[m][n][i]);
      rmin[m][i] = mn;
    }
#pragma unroll
  for (int msk = 1; msk < 16; msk <<= 1)
#pragma unroll
    for (int m = 0; m < 4; ++m)
#pragma unroll
      for (int i = 0; i < 4; ++i)
        rmin[m][i] = fminf(rmin[m][i], __shfl_xor(rmin[m][i], msk, 64));
  if (l15 == 0) {
#pragma unroll
    for (int m = 0; m < 4; ++m)
#pragma unroll
      for (int i = 0; i < 4; ++i)
        redmin[w * 64 + m * 16 + lhi * 4 + i] = rmin[m][i];
  }
  __syncthreads();
  if (t < 64) {
    float mn = redmin[t];
#pragma unroll
    for (int w2 = 1; w2 < 4; ++w2) mn = fminf(mn, redmin[w2 * 64 + t]);
    gmin[t] = mn;
  }
  __syncthreads();
#pragma unroll
  for (int m = 0; m < 4; ++m) {
#pragma unroll
    for (int i = 0; i < 4; ++i) {
      const int row = m * 16 + lhi * 4 + i;
      const float M = gmin[row];
      float se = 0.f, sge = 0.f;
#pragma unroll
      for (int n = 0; n < 8; ++n) {
        const float g = c2r[n] - 2.f * acc[m][n][i];
        const float gm = g - M;
        const float e = __expf(-alpha * gm);
        se += e;
        sge += gm * e;
      }
#pragma unroll
      for (int msk = 1; msk < 16; msk <<= 1) {
        se += __shfl_xor(se, msk, 64);
        sge += __shfl_xor(sge, msk, 64);
      }
      if (l15 == 0) {
        redse[w * 64 + row] = se;
        redsge[w * 64 + row] = sge;
      }
    }
  }
  __syncthreads();
  if (t < 64) {
    float Se = 0.f, Sge = 0.f;
#pragma unroll
    for (int w2 = 0; w2 < 4; ++w2) {
      Se += redse[w2 * 64 + t];
      Sge += redsge[w2 * 64 + t];
    }
    float v = gmin[t] + Sge / Se + x2s[t];
#pragma unroll
    for (int msk = 1; msk < 64; msk <<= 1) v += __shfl_xor(v, msk, 64);
    if (t == 0) partials[bid] = v;
  }
}

// ---------- final deterministic reduction ----------
__global__ __launch_bounds__(256) void final_kernel(const uint8_t* __restrict__ ws,
                                                    const float* __restrict__ lambdp,
                                                    float* __restrict__ out) {
  const float* partials = (const float*)(ws + WS_PART);
  const int t = threadIdx.x;
  float s = 0.f;
  for (int i = t; i < NBLK; i += 256) s += partials[i];
#pragma unroll
  for (int msk = 1; msk < 64; msk <<= 1) s += __shfl_xor(s, msk, 64);
  __shared__ float red[4];
  if ((t & 63) == 0) red[t >> 6] = s;
  __syncthreads();
  if (t == 0)
    out[0] = lambdp[0] * (red[0] + red[1] + red[2] + red[3]) * (1.0f / (float)NPTS);
}

extern "C" void kernel_launch(void* const* d_in, const int* in_sizes, int n_in,
                              void* d_out, int out_size, void* d_ws, size_t ws_size,
                              hipStream_t stream) {
  const float* emb = (const float*)d_in[0];
  const float* cent = (const float*)d_in[1];
  const float* alphap = (const float*)d_in[2];
  const float* lambdp = (const float*)d_in[3];
  float* out = (float*)d_out;
  uint8_t* ws = (uint8_t*)d_ws;

  prep_kernel<<<NCL, 128, 0, stream>>>(cent, ws);
  main_kernel<<<NBLK, NTHREADS, 0, stream>>>(emb, ws, alphap);
  final_kernel<<<1, 256, 0, stream>>>(ws, lambdp, out);
}

// Round 12
// 99.615 us; speedup vs baseline: 5.9790x; 1.0435x over previous
//
#include <hip/hip_runtime.h>
#include <stdint.h>

#define NPTS   131072
#define DEMB   512
#define NCL    512
#define BM     64
#define NCHUNK 8
#define NTHREADS 256
#define NBLK   (NPTS / BM)          // 2048

typedef __attribute__((ext_vector_type(4))) float f32x4;

// ---- workspace layout (bytes) ----
// [0, 256KB)  : fp8 centroid fragments: frag (ch,w,kk,n) = 512B contiguous at
//               ch*32768 + w*8192 + kk*4096 + n*512; lane l holds bytes l*8..+8
//               = clusters col (w*128+n*16+l15), k = ch*64+kk*32+lhi*8..+8.
// [256KB,+2KB): c2[k] = ||c_k||^2 (f32)
// [258KB,+8KB): per-block partial sums (f32, 2048)
#define WS_CB   0u
#define WS_C2   262144u
#define WS_PART 264192u

static __device__ __forceinline__ float sq4(f32x4 v) {
  return v[0] * v[0] + v[1] * v[1] + v[2] * v[2] + v[3] * v[3];
}

// ---- pinned-schedule load/wait primitives (volatile asm keeps program order) ----
#define LOAD_B8F(DST, BASE)                                                    \
  asm volatile("global_load_dwordx2 %0, %8, off\n\t"                           \
               "global_load_dwordx2 %1, %8, off offset:512\n\t"                \
               "global_load_dwordx2 %2, %8, off offset:1024\n\t"               \
               "global_load_dwordx2 %3, %8, off offset:1536\n\t"               \
               "global_load_dwordx2 %4, %8, off offset:2048\n\t"               \
               "global_load_dwordx2 %5, %8, off offset:2560\n\t"               \
               "global_load_dwordx2 %6, %8, off offset:3072\n\t"               \
               "global_load_dwordx2 %7, %8, off offset:3584"                   \
               : "=&v"((DST)[0]), "=&v"((DST)[1]), "=&v"((DST)[2]),            \
                 "=&v"((DST)[3]), "=&v"((DST)[4]), "=&v"((DST)[5]),            \
                 "=&v"((DST)[6]), "=&v"((DST)[7])                              \
               : "v"(BASE)                                                     \
               : "memory")

#define LOAD_E4(D, P)                                                          \
  asm volatile("global_load_dwordx4 %0, %4, off\n\t"                           \
               "global_load_dwordx4 %1, %4, off offset:16\n\t"                 \
               "global_load_dwordx4 %2, %4, off offset:32\n\t"                 \
               "global_load_dwordx4 %3, %4, off offset:48"                     \
               : "=&v"(D[0]), "=&v"(D[1]), "=&v"(D[2]), "=&v"(D[3])            \
               : "v"(P)                                                        \
               : "memory")

#define WAITV(N)                                                               \
  do {                                                                         \
    asm volatile("s_waitcnt vmcnt(" #N ")" ::: "memory");                      \
    __builtin_amdgcn_sched_barrier(0);                                         \
  } while (0)

#define BAR()                                                                  \
  do {                                                                         \
    asm volatile("s_waitcnt lgkmcnt(0)" ::: "memory");                         \
    __builtin_amdgcn_s_barrier();                                              \
  } while (0)

// ---------- prep: c2 + fp8 centroid fragments in register-load layout ----------
__global__ __launch_bounds__(128) void prep_kernel(const float* __restrict__ cent,
                                                   uint8_t* __restrict__ ws) {
  const int k = blockIdx.x;
  const int t = threadIdx.x;
  float4 v = ((const float4*)(cent + (size_t)k * DEMB))[t];
  float sq = v.x * v.x + v.y * v.y + v.z * v.z + v.w * v.w;
#pragma unroll
  for (int m = 1; m < 64; m <<= 1) sq += __shfl_xor(sq, m, 64);
  __shared__ float red[2];
  if ((t & 63) == 0) red[t >> 6] = sq;
  __syncthreads();
  if (t == 0) ((float*)(ws + WS_C2))[k] = red[0] + red[1];

  // pack 4 f32 -> 4 fp8 (e4m3, RNE) via HW cvt
  int p = __builtin_amdgcn_cvt_pk_fp8_f32(v.x, v.y, 0, false);
  p = __builtin_amdgcn_cvt_pk_fp8_f32(v.z, v.w, p, true);

  const int d = t * 4;
  const int ch = d >> 6;
  const int dd = d & 63;
  const int kk = dd >> 5;
  const int lhi = (dd >> 3) & 3;
  const int w = k >> 7;
  const int n = (k >> 4) & 7;
  const int l15 = k & 15;
  const int lane = lhi * 16 + l15;
  const uint32_t off = (uint32_t)(ch * 32768 + w * 8192 + kk * 4096 + n * 512 +
                                  lane * 8 + (dd & 7));
  *(uint32_t*)(ws + WS_CB + off) = (uint32_t)p;
}

// ---------- fused fp8 GEMM + softmin: 4-wave block, BM=64, full 512 cols ----------
// 2 blocks/CU co-resident; B double-buffered in regs, issued at body top.
__global__ __launch_bounds__(NTHREADS, 2) void main_kernel(
    const float* __restrict__ emb, const uint8_t* __restrict__ ws,
    const float* __restrict__ alphap) {
  __shared__ uint8_t Ab[2][4096];      // A dbuf [64 rows][64 k] fp8, slot-XOR swizzled
  __shared__ float redmin[256];        // [4 waves][64 rows]
  __shared__ float redse[256];
  __shared__ float redsge[256];
  __shared__ float gmin[64];
  __shared__ float x2s[64];

  const int t = threadIdx.x;
  const int w = t >> 6;                // wave 0..3 -> cols [128w, 128w+128)
  const int l = t & 63;
  const int l15 = l & 15;
  const int lhi = l >> 4;
  const int bid = blockIdx.x;
  const size_t row0 = (size_t)bid * BM;

  float* partials = (float*)(ws + WS_PART);

  f32x4 acc[4][8];
#pragma unroll
  for (int m = 0; m < 4; ++m)
#pragma unroll
    for (int n = 0; n < 8; ++n) acc[m][n] = (f32x4){0.f, 0.f, 0.f, 0.f};

  // x staging: thread -> row r = t>>2, float cols [q*16, q*16+16) of each chunk
  const int r = t >> 2;
  const int q = t & 3;
  const float* xge = emb + (row0 + r) * DEMB + q * 16;
  uint32_t xoff[2];
#pragma unroll
  for (int j = 0; j < 2; ++j)
    xoff[j] = (uint32_t)r * 64u + (uint32_t)(((2 * q + j) ^ (r & 7)) << 3);

  float x2a = 0.f;

  // per-wave per-lane B base; frag (ch,kk,n) at + ch*32768 + kk*4096 + n*512
  const uint8_t* fbw = ws + WS_CB + (uint32_t)w * 8192u + (uint32_t)l * 8u;

  long bA[16], bB[16];
  f32x4 ev0[4], ev1[4];

#define STAGE_FROM(EV, DSTBUF)                                                 \
  do {                                                                         \
    uint8_t* _an = (DSTBUF);                                                   \
    _Pragma("unroll")                                                          \
    for (int j = 0; j < 2; ++j) {                                              \
      f32x4 a = EV[2 * j], b = EV[2 * j + 1];                                  \
      x2a += sq4(a) + sq4(b);                                                  \
      uint2 u;                                                                 \
      int p0 = __builtin_amdgcn_cvt_pk_fp8_f32(a[0], a[1], 0, false);          \
      p0 = __builtin_amdgcn_cvt_pk_fp8_f32(a[2], a[3], p0, true);              \
      int p1 = __builtin_amdgcn_cvt_pk_fp8_f32(b[0], b[1], 0, false);          \
      p1 = __builtin_amdgcn_cvt_pk_fp8_f32(b[2], b[3], p1, true);              \
      u.x = (uint32_t)p0;                                                      \
      u.y = (uint32_t)p1;                                                      \
      *(uint2*)(_an + xoff[j]) = u;                                            \
    }                                                                          \
  } while (0)

  // ---- prologue: E[0]->ev0, E[1]->ev1, B[0]->bA; retire E[0]; stage A[0] ----
  LOAD_E4(ev0, xge);
  LOAD_E4(ev1, xge + 64);
  LOAD_B8F(&bA[0], fbw);
  LOAD_B8F(&bA[8], fbw + 4096);
  WAITV(20);                           // retires E[0]; E[1](4)+B[0](16) in flight
  STAGE_FROM(ev0, &Ab[0][0]);
  BAR();

// Body ch: [top] issue E[ch+2](4) then B[ch+1](16) into the OTHER B buffer;
// WAITV retires B[ch]+E[ch+1] (both issued a full body earlier -> no stall);
// MFMA on BCUR; stage A[ch+1] from EVS regs; BAR.
// Ledger: top outstanding 20 = E[ch+1](4)+B[ch](16); after issues 40;
//   bodies 0-5 WAITV(20); body 6 (no E issue, 36) WAITV(16); body 7 WAITV(0).
#define CHUNK_BODY(CH, BCUR, BNEXT, EVN, EVS, VN)                              \
  {                                                                            \
    if ((CH) + 2 < NCHUNK)                                                     \
      LOAD_E4(EVN, xge + ((CH) + 2) * 64);                                     \
    if ((CH) + 1 < NCHUNK) {                                                   \
      const uint8_t* nb = fbw + (uint32_t)((CH) + 1) * 32768u;                 \
      LOAD_B8F(&BNEXT[0], nb);                                                 \
      LOAD_B8F(&BNEXT[8], nb + 4096);                                          \
    }                                                                          \
    const uint8_t* xb = &Ab[(CH) & 1][0];                                      \
    WAITV(VN);                                                                 \
    __builtin_amdgcn_s_setprio(1);                                             \
    _Pragma("unroll")                                                          \
    for (int kk = 0; kk < 2; ++kk) {                                           \
      const uint32_t swz = (uint32_t)(((kk * 4 + lhi) ^ (l15 & 7)) << 3);      \
      long af[4];                                                              \
      _Pragma("unroll")                                                        \
      for (int m = 0; m < 4; ++m)                                              \
        af[m] = *(const long*)(xb + (uint32_t)(m * 16 + l15) * 64u + swz);     \
      _Pragma("unroll")                                                        \
      for (int m = 0; m < 4; ++m)                                              \
        _Pragma("unroll")                                                      \
        for (int n = 0; n < 8; ++n)                                            \
          acc[m][n] = __builtin_amdgcn_mfma_f32_16x16x32_fp8_fp8(              \
              af[m], BCUR[kk * 8 + n], acc[m][n], 0, 0, 0);                    \
    }                                                                          \
    __builtin_amdgcn_s_setprio(0);                                             \
    if ((CH) + 1 < NCHUNK)                                                     \
      STAGE_FROM(EVS, &Ab[((CH) + 1) & 1][0]);                                 \
    BAR();                                                                     \
  }

  CHUNK_BODY(0, bA, bB, ev0, ev1, 20)
  CHUNK_BODY(1, bB, bA, ev1, ev0, 20)
  CHUNK_BODY(2, bA, bB, ev0, ev1, 20)
  CHUNK_BODY(3, bB, bA, ev1, ev0, 20)
  CHUNK_BODY(4, bA, bB, ev0, ev1, 20)
  CHUNK_BODY(5, bB, bA, ev1, ev0, 20)
  CHUNK_BODY(6, bA, bB, ev0, ev1, 16)
  CHUNK_BODY(7, bB, bA, ev1, ev0, 0)
#undef CHUNK_BODY
#undef STAGE_FROM

  // ---- epilogue: g = c2 - 2*s ; val_row = min + sum((g-M)e)/sum(e) + x2 ----
  const float alpha = alphap[0];
  float c2r[8];
  {
    const float* c2p = (const float*)(ws + WS_C2) + w * 128 + l15;
    asm volatile("global_load_dword %0, %8, off\n\t"
                 "global_load_dword %1, %8, off offset:64\n\t"
                 "global_load_dword %2, %8, off offset:128\n\t"
                 "global_load_dword %3, %8, off offset:192\n\t"
                 "global_load_dword %4, %8, off offset:256\n\t"
                 "global_load_dword %5, %8, off offset:320\n\t"
                 "global_load_dword %6, %8, off offset:384\n\t"
                 "global_load_dword %7, %8, off offset:448"
                 : "=&v"(c2r[0]), "=&v"(c2r[1]), "=&v"(c2r[2]), "=&v"(c2r[3]),
                   "=&v"(c2r[4]), "=&v"(c2r[5]), "=&v"(c2r[6]), "=&v"(c2r[7])
                 : "v"(c2p)
                 : "memory");
    asm volatile("s_waitcnt vmcnt(0)" ::: "memory");
    __builtin_amdgcn_sched_barrier(0);
  }

  // per-row x2: 4 threads per row; one writer per row (r = t>>2 unique in block)
  x2a += __shfl_xor(x2a, 1, 64);
  x2a += __shfl_xor(x2a, 2, 64);
  if ((l & 3) == 0) x2s[r] = x2a;

  float rmin[4][4];
#pragma unroll
  for (int m = 0; m < 4; ++m)
#pragma unroll
    for (int i = 0; i < 4; ++i) {
      float mn = c2r[0] - 2.f * acc[m][0][i];
#pragma unroll
      for (int n = 1; n < 8; ++n) mn = fminf(mn, c2r[n] - 2.f * acc[m][n][i]);
      rmin[m][i] = mn;
    }
#pragma unroll
  for (int msk = 1; msk < 16; msk <<= 1)
#pragma unroll
    for (int m = 0; m < 4; ++m)
#pragma unroll
      for (int i = 0; i < 4; ++i)
        rmin[m][i] = fminf(rmin[m][i], __shfl_xor(rmin[m][i], msk, 64));
  if (l15 == 0) {
#pragma unroll
    for (int m = 0; m < 4; ++m)
#pragma unroll
      for (int i = 0; i < 4; ++i)
        redmin[w * 64 + m * 16 + lhi * 4 + i] = rmin[m][i];
  }
  __syncthreads();
  if (t < 64) {
    float mn = redmin[t];
#pragma unroll
    for (int w2 = 1; w2 < 4; ++w2) mn = fminf(mn, redmin[w2 * 64 + t]);
    gmin[t] = mn;
  }
  __syncthreads();
#pragma unroll
  for (int m = 0; m < 4; ++m) {
#pragma unroll
    for (int i = 0; i < 4; ++i) {
      const int row = m * 16 + lhi * 4 + i;
      const float M = gmin[row];
      float se = 0.f, sge = 0.f;
#pragma unroll
      for (int n = 0; n < 8; ++n) {
        const float g = c2r[n] - 2.f * acc[m][n][i];
        const float gm = g - M;
        const float e = __expf(-alpha * gm);
        se += e;
        sge += gm * e;
      }
#pragma unroll
      for (int msk = 1; msk < 16; msk <<= 1) {
        se += __shfl_xor(se, msk, 64);
        sge += __shfl_xor(sge, msk, 64);
      }
      if (l15 == 0) {
        redse[w * 64 + row] = se;
        redsge[w * 64 + row] = sge;
      }
    }
  }
  __syncthreads();
  if (t < 64) {
    float Se = 0.f, Sge = 0.f;
#pragma unroll
    for (int w2 = 0; w2 < 4; ++w2) {
      Se += redse[w2 * 64 + t];
      Sge += redsge[w2 * 64 + t];
    }
    float v = gmin[t] + Sge / Se + x2s[t];
#pragma unroll
    for (int msk = 1; msk < 64; msk <<= 1) v += __shfl_xor(v, msk, 64);
    if (t == 0) partials[bid] = v;
  }
}

// ---------- final deterministic reduction ----------
__global__ __launch_bounds__(256) void final_kernel(const uint8_t* __restrict__ ws,
                                                    const float* __restrict__ lambdp,
                                                    float* __restrict__ out) {
  const float* partials = (const float*)(ws + WS_PART);
  const int t = threadIdx.x;
  float s = 0.f;
  for (int i = t; i < NBLK; i += 256) s += partials[i];
#pragma unroll
  for (int msk = 1; msk < 64; msk <<= 1) s += __shfl_xor(s, msk, 64);
  __shared__ float red[4];
  if ((t & 63) == 0) red[t >> 6] = s;
  __syncthreads();
  if (t == 0)
    out[0] = lambdp[0] * (red[0] + red[1] + red[2] + red[3]) * (1.0f / (float)NPTS);
}

extern "C" void kernel_launch(void* const* d_in, const int* in_sizes, int n_in,
                              void* d_out, int out_size, void* d_ws, size_t ws_size,
                              hipStream_t stream) {
  const float* emb = (const float*)d_in[0];
  const float* cent = (const float*)d_in[1];
  const float* alphap = (const float*)d_in[2];
  const float* lambdp = (const float*)d_in[3];
  float* out = (float*)d_out;
  uint8_t* ws = (uint8_t*)d_ws;

  prep_kernel<<<NCL, 128, 0, stream>>>(cent, ws);
  main_kernel<<<NBLK, NTHREADS, 0, stream>>>(emb, ws, alphap);
  final_kernel<<<1, 256, 0, stream>>>(ws, lambdp, out);
}